// Round 8
// baseline (58.485 us; speedup 1.0000x reference)
//
#include <hip/hip_runtime.h>
#include <hip/hip_bf16.h>

// DivEncLayer via MFMA, R8. per (b,q): z = W1^T x + b1; out = sum_h w2p*elu(z) + b2p.
// B=32768, Q=128, S=8, H=32, f32 I/O; bf16 MFMA dense1, f32 epilogue.
//
// R7 -> R8: R7's launch_bounds(512,6) cut the VGPR budget to ~85 < working set -> scratch
// spills (WRITE_SIZE 16->76MB, FETCH +28MB, VALUBusy 31%). Revert to the R6 kernel and
// change ONE thing: 128 b-rows/block (2 subs) -> 1024 blocks x 8 waves = 32 waves/CU,
// double the stall coverage of R6's 16/CU. launch_bounds stays (512,4): budget 128,
// measured 56 VGPR -> 8 waves/SIMD feasible; slab 9.2KB -> 4 blocks/CU fits LDS.

#define QN 128
#define SN 8
#define HN 32
#define XROW 1024
#define BN_EPS 1e-3f

typedef short bf16x8 __attribute__((ext_vector_type(8)));
typedef float f32x16 __attribute__((ext_vector_type(16)));
typedef unsigned int u32;

#define WS_A_BYTES (QN * 64 * 16)                 // A1pack[q][lane] 16B (hi lanes zero)
#define WS_C_OFF   WS_A_BYTES
#define WS_C_BYTES (QN * 32 * 4)                  // c_init[q][half*16+r] = b1 (f32, reg order)
#define WS_W_OFF   (WS_C_OFF + WS_C_BYTES)
#define WS_W_BYTES (QN * 32 * 4)                  // w2p[q][half*16+r]   (f32, reg order)
#define WS_B2_OFF  (WS_W_OFF + WS_W_BYTES)        // b2p[q]

static __device__ __forceinline__ u32 pkbf(float lo, float hi) {
    union { __hip_bfloat162 h2; u32 u; } c;
    c.h2 = __float22bfloat162_rn(float2{lo, hi});
    return c.u;
}

__global__ void divenc_prep(const float* __restrict__ W1, const float* __restrict__ b1,
                            const float* __restrict__ gamma_, const float* __restrict__ beta_,
                            const float* __restrict__ mmean, const float* __restrict__ mvar,
                            const float* __restrict__ W2, const float* __restrict__ b2,
                            unsigned char* __restrict__ ws)
{
    const int q = blockIdx.x;        // 0..127
    const int m = threadIdx.x;       // 0..63

    u32 d0 = 0, d1 = 0, d2 = 0, d3 = 0;
    if (m < 32) {                    // A[m][k] = W1[q][k][m], k pairs per dword
        d0 = pkbf(W1[(q*SN + 0)*HN + m], W1[(q*SN + 1)*HN + m]);
        d1 = pkbf(W1[(q*SN + 2)*HN + m], W1[(q*SN + 3)*HN + m]);
        d2 = pkbf(W1[(q*SN + 4)*HN + m], W1[(q*SN + 5)*HN + m]);
        d3 = pkbf(W1[(q*SN + 6)*HN + m], W1[(q*SN + 7)*HN + m]);
    }
    ((uint4*)ws)[q*64 + m] = uint4{d0, d1, d2, d3};

    float* wsC  = (float*)(ws + WS_C_OFF);
    float* wsW  = (float*)(ws + WS_W_OFF);
    float* wsB2 = (float*)(ws + WS_B2_OFF);
    if (m < 32) {                    // D-reg order: h = (r&3) + 8*(r>>2) + 4*half
        const int half = m >> 4, r = m & 15;
        const int h = (r & 3) + 8*(r >> 2) + 4*half;
        wsC[q*32 + m] = b1[q*HN + h];
        float inv = gamma_[q*HN+h] * rsqrtf(mvar[q*HN+h] + BN_EPS);
        wsW[q*32 + m] = inv * W2[q*HN + h];
    }
    if (m == 0) {
        float acc = b2[q];
        for (int h = 0; h < HN; ++h) {
            float inv = gamma_[q*HN+h] * rsqrtf(mvar[q*HN+h] + BN_EPS);
            acc += (beta_[q*HN+h] - mmean[q*HN+h]*inv) * W2[q*HN+h];
        }
        wsB2[q] = acc;
    }
}

__global__ __launch_bounds__(512, 4)
void divenc_mfma(const float* __restrict__ x, const unsigned char* __restrict__ ws,
                 float* __restrict__ out)
{
    const int lane = threadIdx.x & 63;
    const int wv   = threadIdx.x >> 6;   // 0..7
    const int half = lane >> 5;
    const int bl   = lane & 31;
    const int b0   = blockIdx.x * 128;
    const int q0   = blockIdx.y * 32;

    const uint4* wsA  = (const uint4*)ws;
    const float* wsC  = (const float*)(ws + WS_C_OFF);
    const float* wsW  = (const float*)(ws + WS_W_OFF);
    const float* wsB2 = (const float*)(ws + WS_B2_OFF);

    __shared__ float slab[2][128][9];    // 9.2 KiB, double-buffered across qg

    #pragma unroll
    for (int qg = 0; qg < 4; ++qg) {
        const int q = q0 + qg*8 + wv;

        union { uint4 u; bf16x8 v; } A1, A2;
        A1.u = wsA[q*64 + lane];          // W1 in lanes<32 (k0-7), zeros above
        A2.u = wsA[q*64 + (lane ^ 32)];   // same bytes -> W1 in k8-15 slots

        f32x16 cini;
        const float* cp_ = wsC + q*32 + half*16;
        #pragma unroll
        for (int r = 0; r < 16; ++r) cini[r] = cp_[r];
        float w2r[16];
        const float* wp_ = wsW + q*32 + half*16;
        #pragma unroll
        for (int r = 0; r < 16; ++r) w2r[r] = wp_[r];
        const float b2p = wsB2[q];

        const float* xq = x + (size_t)b0 * XROW + q * SN;
        float4 xa = *(const float4*)(xq + (size_t)lane * XROW);
        float4 xc = *(const float4*)(xq + (size_t)lane * XROW + 4);

        #pragma unroll
        for (int sub = 0; sub < 2; ++sub) {
            // prefetch next sub's x (clamped re-read on last iter: L1-hit, harmless)
            const int nsub = (sub < 1) ? sub + 1 : sub;
            const float* np = xq + (size_t)(nsub*64 + lane) * XROW;
            float4 na = *(const float4*)np;
            float4 nc = *(const float4*)(np + 4);

            union { uint4 u; bf16x8 v; } B;
            B.u = uint4{ pkbf(xa.x, xa.y), pkbf(xa.z, xa.w),
                         pkbf(xc.x, xc.y), pkbf(xc.z, xc.w) };

            f32x16 D0 = __builtin_amdgcn_mfma_f32_32x32x16_bf16(A1.v, B.v, cini, 0, 0, 0);
            f32x16 D1 = __builtin_amdgcn_mfma_f32_32x32x16_bf16(A2.v, B.v, cini, 0, 0, 0);

            float p0 = 0.f, p1 = 0.f;
            #pragma unroll
            for (int r = 0; r < 16; ++r) {
                float z0 = D0[r];
                float e0 = __expf(fminf(z0, 0.f)) - 1.f;
                p0 = fmaf(fmaxf(z0, e0), w2r[r], p0);
                float z1 = D1[r];
                float e1 = __expf(fminf(z1, 0.f)) - 1.f;
                p1 = fmaf(fmaxf(z1, e1), w2r[r], p1);
            }
            p0 += __shfl_xor(p0, 32);     // combine the two h-halves (same b-col)
            p1 += __shfl_xor(p1, 32);

            const float v = (half ? p1 : p0) + b2p;
            slab[qg & 1][sub*64 + half*32 + bl][wv] = v;

            xa = na; xc = nc;
        }

        __syncthreads();                  // slab[qg&1] complete; qg+1 uses other slab
        {
            const int row = threadIdx.x >> 2;          // 0..127
            const int cp  = (threadIdx.x & 3) * 2;     // 0,2,4,6
            float2 vv;
            vv.x = slab[qg & 1][row][cp + 0];
            vv.y = slab[qg & 1][row][cp + 1];
            *(float2*)(out + (size_t)(b0 + row) * QN + q0 + qg*8 + cp) = vv;
        }
    }
}

extern "C" void kernel_launch(void* const* d_in, const int* in_sizes, int n_in,
                              void* d_out, int out_size, void* d_ws, size_t ws_size,
                              hipStream_t stream) {
    const float* x      = (const float*)d_in[0];
    const float* W1     = (const float*)d_in[1];
    const float* b1     = (const float*)d_in[2];
    const float* gamma_ = (const float*)d_in[3];
    const float* beta_  = (const float*)d_in[4];
    const float* mmean  = (const float*)d_in[5];
    const float* mvar   = (const float*)d_in[6];
    const float* W2     = (const float*)d_in[7];
    const float* b2     = (const float*)d_in[8];
    float* out = (float*)d_out;
    unsigned char* ws = (unsigned char*)d_ws;

    const int Btot = in_sizes[0] / XROW;              // 32768

    divenc_prep<<<QN, 64, 0, stream>>>(W1, b1, gamma_, beta_, mmean, mvar, W2, b2, ws);
    divenc_mfma<<<dim3(Btot / 128, QN / 32), 512, 0, stream>>>(x, ws, out);
}